// Round 5
// baseline (40.126 us; speedup 1.0000x reference)
//
#include <hip/hip_runtime.h>

#define T_DIM 64
#define N_DIM 128
#define BATCH 2
#define HIDW  32

// Workspace layout (floats):
//   up   : [B][T][N][32]   @ 0        (524288)
//   pp   : [B][T][N][32]   @ 524288
//   h    : [B][N][T][32]   @ 1048576  (n-major)
//   Hsum : [2][32][32]     @ 1572864  (sum_k H[l,k], precomputed by kernel 1)

__device__ __forceinline__ int rfl(int x) { return __builtin_amdgcn_readfirstlane(x); }

// ---------------------------------------------------------------------------
// A kernel: (optional input projection) + temporal mix.
// grid = B*N = 256 blocks, 512 threads.  wave fg = tid>>6 (f-chunk of 4),
// lane t = tid&63.  w[t,f] = sum_u At[t,u]*h[u,f]; up=s1*h+s3*w; pp=s0*h+s2*w
// Broadcast operands (W1, h-rows for non-PROJ) read uniformly from global
// (s_load path); lane-distinct (At, x) from padded conflict-free LDS.
// ---------------------------------------------------------------------------
template<bool PROJ>
__global__ __launch_bounds__(512) void k_temporal(
    const float* __restrict__ src,     // PROJ ? x : h (n-major)
    const float* __restrict__ At,
    const float* __restrict__ W1, const float* __restrict__ b1,
    const float* __restrict__ s,
    const float* __restrict__ H, float* __restrict__ Hsum_ws,
    float* __restrict__ up, float* __restrict__ pp)
{
    __shared__ float At_s[64 * 68];    // b128 read at t*68+u0: bank 17t+u0/4, conflict-free
    __shared__ float xs[64 * 36];      // PROJ: x rows, b128 at t*36+k0: bank 9t+k0/4
    __shared__ float h_loc[64 * 36];   // PROJ: projected h, broadcast b128 reads

    const int tid = threadIdx.x;
    const int b   = blockIdx.x >> 7;
    const int n   = blockIdx.x & 127;
    const int fg  = tid >> 6;
    const int t   = tid & 63;
    const int fg4u = rfl(fg * 4);

    const float s0v = s[0], s1v = s[1], s2v = s[2], s3v = s[3];

    // one-time Hsum precompute (blocks 0..3): Hsum[l][e] = sum_k H[l][k][e]
    if (PROJ && blockIdx.x < 4) {
        int idx = blockIdx.x * 512 + tid;          // 0..2047
        int l = idx >> 10, rem = idx & 1023;
        const float* Hl = H + l * 4096;
        Hsum_ws[idx] = Hl[rem] + Hl[1024 + rem] + Hl[2048 + rem] + Hl[3072 + rem];
    }

    // stage At [64][64] -> [64][68]
#pragma unroll
    for (int i = 0; i < 8; ++i) {
        int p = tid + 512 * i;
        At_s[(p >> 6) * 68 + (p & 63)] = At[p];
    }

    float h0, h1, h2, h3;
    if (PROJ) {
        // stage x rows x[b, t*128+n, :] -> xs[64][36]
        {
            int tt = tid >> 3, c4 = tid & 7;
            float4 v = *(const float4*)(src + ((size_t)(b * 8192 + tt * 128 + n)) * 32 + c4 * 4);
            *(float4*)&xs[tt * 36 + c4 * 4] = v;
        }
        __syncthreads();
        // h = x @ W1 + b1 ; W1 read uniformly from global
        const float* W1u = W1 + fg4u;
        float4 bv = *(const float4*)(b1 + fg4u);
        h0 = bv.x; h1 = bv.y; h2 = bv.z; h3 = bv.w;
#pragma unroll
        for (int k4 = 0; k4 < 8; ++k4) {
            float4 xv = *(const float4*)&xs[t * 36 + k4 * 4];
            float4 w0 = *(const float4*)(W1u + (k4 * 4 + 0) * 32);
            float4 w1 = *(const float4*)(W1u + (k4 * 4 + 1) * 32);
            float4 w2 = *(const float4*)(W1u + (k4 * 4 + 2) * 32);
            float4 w3 = *(const float4*)(W1u + (k4 * 4 + 3) * 32);
            h0 += xv.x * w0.x + xv.y * w1.x + xv.z * w2.x + xv.w * w3.x;
            h1 += xv.x * w0.y + xv.y * w1.y + xv.z * w2.y + xv.w * w3.y;
            h2 += xv.x * w0.z + xv.y * w1.z + xv.z * w2.z + xv.w * w3.z;
            h3 += xv.x * w0.w + xv.y * w1.w + xv.z * w2.w + xv.w * w3.w;
        }
        float4 hv; hv.x = h0; hv.y = h1; hv.z = h2; hv.w = h3;
        *(float4*)&h_loc[t * 36 + fg * 4] = hv;    // bank 9t+fg: conflict-free
        __syncthreads();
    } else {
        __syncthreads();                            // At_s ready
        float4 hv = *(const float4*)(src + (((size_t)(b * 128 + n)) * 64 + t) * 32 + fg * 4);
        h0 = hv.x; h1 = hv.y; h2 = hv.z; h3 = hv.w;
    }

    // temporal mix: At lane-distinct b128 from LDS; h broadcast:
    //   PROJ -> LDS broadcast (values just computed); else -> uniform global
    float w0 = 0.f, w1 = 0.f, w2 = 0.f, w3 = 0.f;
    const float* hrow = PROJ ? nullptr
                             : (src + rfl((b * 128 + n) * 2048) + fg4u);
#pragma unroll
    for (int u4 = 0; u4 < 16; ++u4) {
        float4 av = *(const float4*)&At_s[t * 68 + u4 * 4];
        float4 g0, g1, g2, g3;
        if (PROJ) {
            g0 = *(const float4*)&h_loc[(u4 * 4 + 0) * 36 + fg * 4];
            g1 = *(const float4*)&h_loc[(u4 * 4 + 1) * 36 + fg * 4];
            g2 = *(const float4*)&h_loc[(u4 * 4 + 2) * 36 + fg * 4];
            g3 = *(const float4*)&h_loc[(u4 * 4 + 3) * 36 + fg * 4];
        } else {
            g0 = *(const float4*)(hrow + (u4 * 4 + 0) * 32);
            g1 = *(const float4*)(hrow + (u4 * 4 + 1) * 32);
            g2 = *(const float4*)(hrow + (u4 * 4 + 2) * 32);
            g3 = *(const float4*)(hrow + (u4 * 4 + 3) * 32);
        }
        w0 += av.x * g0.x + av.y * g1.x + av.z * g2.x + av.w * g3.x;
        w1 += av.x * g0.y + av.y * g1.y + av.z * g2.y + av.w * g3.y;
        w2 += av.x * g0.z + av.y * g1.z + av.z * g2.z + av.w * g3.z;
        w3 += av.x * g0.w + av.y * g1.w + av.z * g2.w + av.w * g3.w;
    }
    float4 u4v, p4v;
    u4v.x = s1v * h0 + s3v * w0;  p4v.x = s0v * h0 + s2v * w0;
    u4v.y = s1v * h1 + s3v * w1;  p4v.y = s0v * h1 + s2v * w1;
    u4v.z = s1v * h2 + s3v * w2;  p4v.z = s0v * h2 + s2v * w2;
    u4v.w = s1v * h3 + s3v * w3;  p4v.w = s0v * h3 + s2v * w3;
    size_t base = ((size_t)((b * 64 + t) * 128 + n)) * 32 + fg * 4;
    *(float4*)(up + base) = u4v;
    *(float4*)(pp + base) = p4v;
}

// ---------------------------------------------------------------------------
// B kernel: spatial mix + graph filter (+ fused output projection if LAST).
// grid = B*T*2 = 256 blocks, 512 threads.  wave fg (f-chunk), lane m.
//   Ah[m,f] = pp[m,f] + sum_n As[mh*64+m, n] * up[n,f]
//   Tv[m,f] = tanh(sum_k Ah[m,k] * Hsum[k,f])
//   LAST: out[m,fo] = sum_k Tv[m,k]*W2[k,fo] + b2[fo]
// up / Hsum / W2 / b2 read uniformly from global; As lane-distinct LDS.
// ---------------------------------------------------------------------------
template<bool LAST>
__global__ __launch_bounds__(512) void k_spatial(
    const float* __restrict__ up, const float* __restrict__ pp,
    const float* __restrict__ As, const float* __restrict__ Hsum_ws, int layer,
    const float* __restrict__ W2, const float* __restrict__ b2,
    float* __restrict__ hout, float* __restrict__ out)
{
    __shared__ float As_s[64 * 132];   // b128 at m*132+n0: bank 33m+n0/4 = m+n0/4
    __shared__ float Ah_s[64 * 36];
    __shared__ float T_s[64 * 36];     // LAST only

    const int tid = threadIdx.x;
    const int b   = blockIdx.x >> 7;
    const int t   = (blockIdx.x >> 1) & 63;
    const int mh  = blockIdx.x & 1;
    const int fg  = tid >> 6;
    const int m   = tid & 63;
    const int fg4u = rfl(fg * 4);

    // stage As half-tile [64][128] -> [64][132]
#pragma unroll
    for (int i = 0; i < 4; ++i) {
        int p = tid + 512 * i;
        int r = p >> 5, g = p & 31;
        float4 v = *(const float4*)(As + ((size_t)(mh * 64 + r)) * 128 + g * 4);
        *(float4*)&As_s[r * 132 + g * 4] = v;
    }
    // acc init from pp (lane-distinct vector load; hides under staging)
    float4 pv = *(const float4*)(pp + (((size_t)(b * 64 + t)) * 128 + mh * 64 + m) * 32 + fg * 4);
    float a0 = pv.x, a1 = pv.y, a2 = pv.z, a3 = pv.w;
    __syncthreads();

    // phase 2: As lane-distinct b128 (LDS), up wave-uniform from global
    const float* urow = up + rfl((b * 64 + t) * 4096) + fg4u;
#pragma unroll 8
    for (int n4 = 0; n4 < 32; ++n4) {
        float4 av = *(const float4*)&As_s[m * 132 + n4 * 4];
        float4 u0 = *(const float4*)(urow + (n4 * 4 + 0) * 32);
        float4 u1 = *(const float4*)(urow + (n4 * 4 + 1) * 32);
        float4 u2 = *(const float4*)(urow + (n4 * 4 + 2) * 32);
        float4 u3 = *(const float4*)(urow + (n4 * 4 + 3) * 32);
        a0 += av.x * u0.x + av.y * u1.x + av.z * u2.x + av.w * u3.x;
        a1 += av.x * u0.y + av.y * u1.y + av.z * u2.y + av.w * u3.y;
        a2 += av.x * u0.z + av.y * u1.z + av.z * u2.z + av.w * u3.z;
        a3 += av.x * u0.w + av.y * u1.w + av.z * u2.w + av.w * u3.w;
    }
    {
        float4 w; w.x = a0; w.y = a1; w.z = a2; w.w = a3;
        *(float4*)&Ah_s[m * 36 + fg * 4] = w;      // bank 9m+fg: conflict-free
    }
    __syncthreads();

    // phase 3: graph filter + tanh; Hsum wave-uniform from workspace
    const float* hsrow = Hsum_ws + rfl(layer * 1024) + fg4u;
    float c0 = 0.f, c1 = 0.f, c2 = 0.f, c3 = 0.f;
#pragma unroll
    for (int k4 = 0; k4 < 8; ++k4) {
        float4 av = *(const float4*)&Ah_s[m * 36 + k4 * 4];
        float4 q0 = *(const float4*)(hsrow + (k4 * 4 + 0) * 32);
        float4 q1 = *(const float4*)(hsrow + (k4 * 4 + 1) * 32);
        float4 q2 = *(const float4*)(hsrow + (k4 * 4 + 2) * 32);
        float4 q3 = *(const float4*)(hsrow + (k4 * 4 + 3) * 32);
        c0 += av.x * q0.x + av.y * q1.x + av.z * q2.x + av.w * q3.x;
        c1 += av.x * q0.y + av.y * q1.y + av.z * q2.y + av.w * q3.y;
        c2 += av.x * q0.z + av.y * q1.z + av.z * q2.z + av.w * q3.z;
        c3 += av.x * q0.w + av.y * q1.w + av.z * q2.w + av.w * q3.w;
    }
    c0 = tanhf(c0); c1 = tanhf(c1); c2 = tanhf(c2); c3 = tanhf(c3);

    if (!LAST) {
        float4 o; o.x = c0; o.y = c1; o.z = c2; o.w = c3;
        // h stored n-major: [b][nglob][t][f]
        *(float4*)(hout + (((size_t)(b * 128 + mh * 64 + m)) * 64 + t) * 32 + fg * 4) = o;
    } else {
        float4 w; w.x = c0; w.y = c1; w.z = c2; w.w = c3;
        *(float4*)&T_s[m * 36 + fg * 4] = w;
        __syncthreads();
        // fused output projection: wave fg covers fo = {fg*2, fg*2+1}
        const int fg2u = rfl(fg * 2);
        float o0 = b2[fg2u], o1 = b2[fg2u + 1];
        const float* w2r = W2 + fg2u;
#pragma unroll
        for (int k4 = 0; k4 < 8; ++k4) {
            float4 tv = *(const float4*)&T_s[m * 36 + k4 * 4];
            float2 v0 = *(const float2*)(w2r + (k4 * 4 + 0) * 16);
            float2 v1 = *(const float2*)(w2r + (k4 * 4 + 1) * 16);
            float2 v2 = *(const float2*)(w2r + (k4 * 4 + 2) * 16);
            float2 v3 = *(const float2*)(w2r + (k4 * 4 + 3) * 16);
            o0 += tv.x * v0.x + tv.y * v1.x + tv.z * v2.x + tv.w * v3.x;
            o1 += tv.x * v0.y + tv.y * v1.y + tv.z * v2.y + tv.w * v3.y;
        }
        float2 o; o.x = o0; o.y = o1;
        *(float2*)(out + (((size_t)(b * 64 + t)) * 128 + mh * 64 + m) * 16 + fg * 2) = o;
    }
}

// ---------------------------------------------------------------------------
extern "C" void kernel_launch(void* const* d_in, const int* in_sizes, int n_in,
                              void* d_out, int out_size, void* d_ws, size_t ws_size,
                              hipStream_t stream)
{
    const float* x   = (const float*)d_in[0];
    const float* At  = (const float*)d_in[1];
    const float* As  = (const float*)d_in[2];
    const float* s   = (const float*)d_in[3];
    const float* H   = (const float*)d_in[4];
    const float* W1  = (const float*)d_in[5];
    const float* b1  = (const float*)d_in[6];
    const float* W2  = (const float*)d_in[7];
    const float* b2  = (const float*)d_in[8];
    float* out = (float*)d_out;

    float* up   = (float*)d_ws;            // 524288 floats
    float* pp   = up + 524288;
    float* h    = pp + 524288;
    float* Hsum = h  + 524288;             // 2048 floats

    k_temporal<true ><<<256, 512, 0, stream>>>(x, At, W1, b1, s, H, Hsum, up, pp);
    k_spatial <false><<<256, 512, 0, stream>>>(up, pp, As, Hsum, 0, W2, b2, h, out);
    k_temporal<false><<<256, 512, 0, stream>>>(h, At, W1, b1, s, H, Hsum, up, pp);
    k_spatial <true ><<<256, 512, 0, stream>>>(up, pp, As, Hsum, 1, W2, b2, h, out);
}